// Round 2
// baseline (693.242 us; speedup 1.0000x reference)
//
#include <hip/hip_runtime.h>
#include <hip/hip_bf16.h>

#define N_NODES 50000
#define N_EDGES 250000
#define NHEAD   12
#define DDIM    64
#define NH      (N_NODES * NHEAD)   /* 600000 rows of 64 */
#define ROW_TILES (NH / 16)         /* 37500 */

typedef __bf16 bf16_t;
typedef __bf16 bf16x8 __attribute__((ext_vector_type(8)));
typedef float  f32x4  __attribute__((ext_vector_type(4)));

__device__ __forceinline__ bf16x8 cvt8(f32x4 a, f32x4 b) {
    bf16x8 r;
    r[0] = (bf16_t)a[0]; r[1] = (bf16_t)a[1]; r[2] = (bf16_t)a[2]; r[3] = (bf16_t)a[3];
    r[4] = (bf16_t)b[0]; r[5] = (bf16_t)b[1]; r[6] = (bf16_t)b[2]; r[7] = (bf16_t)b[3];
    return r;
}

// ---------------- GEMM: ft = X*Wfc^T, res = X*Wres^T, a_l/a_r epilogue ----------------
// X = h viewed as [600000][64] f32 -> bf16 in-register. One wave per 16-row tile.
// mfma_f32_16x16x32_bf16: A row=lane&15, k=(lane>>4)*8+i ; B col=lane&15, same k ;
// D col=lane&15, row=(lane>>4)*4+reg  [m89-verified layout].
__global__ __launch_bounds__(256) void k_gemm(
    const float* __restrict__ h,
    const float* __restrict__ wfc,
    const float* __restrict__ wres,
    const float* __restrict__ attl,
    const float* __restrict__ attr,
    bf16_t* __restrict__ ft,
    bf16_t* __restrict__ resb,
    float* __restrict__ al,
    float* __restrict__ ar)
{
    int wid  = (blockIdx.x * blockDim.x + threadIdx.x) >> 6;
    if (wid >= ROW_TILES) return;
    int lane = threadIdx.x & 63;
    int lr = lane & 15, lg = lane >> 4;
    int r0 = wid << 4;

    const f32x4* hv = reinterpret_cast<const f32x4*>(h);
    const f32x4* wf = reinterpret_cast<const f32x4*>(wfc);
    const f32x4* wr = reinterpret_cast<const f32x4*>(wres);

    // A fragments (shared by both GEMMs): elem offset (r0+lr)*64 + ks*32 + lg*8
    int abase = (r0 + lr) * 16 + lg * 2;              // in f32x4 units
    bf16x8 a0 = cvt8(hv[abase + 0], hv[abase + 1]);
    bf16x8 a1 = cvt8(hv[abase + 8], hv[abase + 9]);

    f32x4 dfc[4], dre[4];
#pragma unroll
    for (int nt = 0; nt < 4; ++nt) {
        int bbase = (nt * 16 + lr) * 16 + lg * 2;     // W[col][k] in f32x4 units
        f32x4 z = {0.f, 0.f, 0.f, 0.f};
        bf16x8 b0 = cvt8(wf[bbase + 0], wf[bbase + 1]);
        bf16x8 b1 = cvt8(wf[bbase + 8], wf[bbase + 9]);
        z = __builtin_amdgcn_mfma_f32_16x16x32_bf16(a0, b0, z, 0, 0, 0);
        z = __builtin_amdgcn_mfma_f32_16x16x32_bf16(a1, b1, z, 0, 0, 0);
        dfc[nt] = z;
        f32x4 y = {0.f, 0.f, 0.f, 0.f};
        bf16x8 c0 = cvt8(wr[bbase + 0], wr[bbase + 1]);
        bf16x8 c1 = cvt8(wr[bbase + 8], wr[bbase + 9]);
        y = __builtin_amdgcn_mfma_f32_16x16x32_bf16(a0, c0, y, 0, 0, 0);
        y = __builtin_amdgcn_mfma_f32_16x16x32_bf16(a1, c1, y, 0, 0, 0);
        dre[nt] = y;
    }

    float pl[4] = {0, 0, 0, 0}, pr[4] = {0, 0, 0, 0};
#pragma unroll
    for (int nt = 0; nt < 4; ++nt) {
#pragma unroll
        for (int j = 0; j < 4; ++j) {
            int row = lg * 4 + j;
            int col = nt * 16 + lr;
            int r   = r0 + row;
            float vf = dfc[nt][j];
            ft[r * 64 + col]   = (bf16_t)vf;
            resb[r * 64 + col] = (bf16_t)dre[nt][j];
            int hh = r % NHEAD;
            pl[j] += vf * attl[hh * 64 + col];
            pr[j] += vf * attr[hh * 64 + col];
        }
    }
    // reduce across the 16 lanes sharing a row group (xor masks < 16 stay in-group)
#pragma unroll
    for (int j = 0; j < 4; ++j) {
#pragma unroll
        for (int m = 1; m < 16; m <<= 1) {
            pl[j] += __shfl_xor(pl[j], m);
            pr[j] += __shfl_xor(pr[j], m);
        }
    }
    if (lr == 0) {
#pragma unroll
        for (int j = 0; j < 4; ++j) {
            al[r0 + lg * 4 + j] = pl[j];
            ar[r0 + lg * 4 + j] = pr[j];
        }
    }
}

// ---------------- CSR build ----------------
__global__ __launch_bounds__(256) void k_zero(int* __restrict__ deg) {
    int i = blockIdx.x * 256 + threadIdx.x;
    if (i < N_NODES) deg[i] = 0;
}

__global__ __launch_bounds__(256) void k_deg(const int* __restrict__ dst, int* __restrict__ deg) {
    int i = blockIdx.x * 256 + threadIdx.x;
    if (i < N_EDGES) atomicAdd(&deg[dst[i]], 1);
}

__global__ __launch_bounds__(1024) void k_scan(const int* __restrict__ deg,
                                               int* __restrict__ rowptr,
                                               int* __restrict__ cursor) {
    __shared__ int s[1024];
    const int CH = (N_NODES + 1023) / 1024;  // 49
    int t = threadIdx.x;
    int base = t * CH;
    int sum = 0;
    for (int i = 0; i < CH; ++i) {
        int idx = base + i;
        if (idx < N_NODES) sum += deg[idx];
    }
    s[t] = sum;
    __syncthreads();
    for (int off = 1; off < 1024; off <<= 1) {
        int v = (t >= off) ? s[t - off] : 0;
        __syncthreads();
        s[t] += v;
        __syncthreads();
    }
    int run = s[t] - sum;  // exclusive prefix of this chunk
    for (int i = 0; i < CH; ++i) {
        int idx = base + i;
        if (idx < N_NODES) {
            rowptr[idx] = run;
            cursor[idx] = run;
            run += deg[idx];
        }
    }
    if (t == 1023) rowptr[N_NODES] = s[1023];
}

__global__ __launch_bounds__(256) void k_fill(const int* __restrict__ src,
                                              const int* __restrict__ dst,
                                              int* __restrict__ cursor,
                                              int* __restrict__ csr_src) {
    int i = blockIdx.x * 256 + threadIdx.x;
    if (i < N_EDGES) {
        int d = dst[i];
        int pos = atomicAdd(&cursor[d], 1);
        csr_src[pos] = src[i];
    }
}

// ---------------- softmax + aggregate + residual + relu ----------------
// One wave per (dst,head); lane = feature d. Single pass: unnormalized weighted
// sum + denominator, normalize at end. No max-subtraction (logits sigma~2.4,
// |e| < ~15 << 88, fp32-exp safe).
__global__ __launch_bounds__(256) void k_agg(
    const int* __restrict__ rowptr, const int* __restrict__ csr_src,
    const float* __restrict__ al, const float* __restrict__ ar,
    const bf16_t* __restrict__ ft, const bf16_t* __restrict__ resb,
    float* __restrict__ out)
{
    int wid = (blockIdx.x * 256 + threadIdx.x) >> 6;
    if (wid >= NH) return;
    int lane = threadIdx.x & 63;
    int d0 = wid / NHEAD;
    int hh = wid - d0 * NHEAD;
    int beg = rowptr[d0], end = rowptr[d0 + 1];
    float ard = ar[wid];
    float acc = 0.f, den = 0.f;
    for (int j = beg; j < end; ++j) {
        int sidx = csr_src[j];
        float e = al[sidx * NHEAD + hh] + ard;
        e = (e > 0.f) ? e : 0.2f * e;          // leaky_relu
        float w = __expf(e);
        den += w;
        acc += w * (float)ft[sidx * 768 + hh * 64 + lane];
    }
    float r = (float)resb[wid * 64 + lane];
    float o = r + acc / den;
    out[wid * 64 + lane] = (o > 0.f ? o : 0.f);
}

extern "C" void kernel_launch(void* const* d_in, const int* in_sizes, int n_in,
                              void* d_out, int out_size, void* d_ws, size_t ws_size,
                              hipStream_t stream) {
    const float* h    = (const float*)d_in[0];
    const float* wfc  = (const float*)d_in[1];
    const float* attl = (const float*)d_in[2];
    const float* attr = (const float*)d_in[3];
    const float* wres = (const float*)d_in[4];
    const int*   src  = (const int*)d_in[5];
    const int*   dst  = (const int*)d_in[6];
    float* out = (float*)d_out;

    char* ws = (char*)d_ws;
    bf16_t* ft     = (bf16_t*)(ws + 0);          //  76,800,000 B
    bf16_t* resb   = (bf16_t*)(ws + 76800000);   //  76,800,000 B
    float*  al     = (float*)(ws + 153600000);   //   2,400,000 B
    float*  ar     = (float*)(ws + 156000000);   //   2,400,000 B
    int*    deg    = (int*)(ws + 158400000);     //     200,448 B
    int*    rowptr = (int*)(ws + 158600448);     //     200,448 B
    int*    cursor = (int*)(ws + 158800896);     //     200,448 B
    int*    csrsrc = (int*)(ws + 159001344);     //   1,000,000 B  (end ~160 MB)

    k_zero<<<(N_NODES + 255) / 256, 256, 0, stream>>>(deg);
    k_deg<<<(N_EDGES + 255) / 256, 256, 0, stream>>>(dst, deg);
    k_scan<<<1, 1024, 0, stream>>>(deg, rowptr, cursor);
    k_fill<<<(N_EDGES + 255) / 256, 256, 0, stream>>>(src, dst, cursor, csrsrc);
    k_gemm<<<ROW_TILES / 4, 256, 0, stream>>>(h, wfc, wres, attl, attr, ft, resb, al, ar);
    k_agg<<<NH / 4, 256, 0, stream>>>(rowptr, csrsrc, al, ar, ft, resb, out);
}

// Round 3
// 628.443 us; speedup vs baseline: 1.1031x; 1.1031x over previous
//
#include <hip/hip_runtime.h>
#include <hip/hip_bf16.h>

#define N_NODES 50000
#define N_EDGES 250000
#define NHEAD   12
#define DDIM    64
#define NH      (N_NODES * NHEAD)   /* 600000 rows of 64 */
#define ROW_TILES (NH / 16)         /* 37500 */

typedef __bf16 bf16_t;
typedef __bf16 bf16x8 __attribute__((ext_vector_type(8)));
typedef float  f32x4  __attribute__((ext_vector_type(4)));

__device__ __forceinline__ bf16x8 cvt8(f32x4 a, f32x4 b) {
    bf16x8 r;
    r[0] = (bf16_t)a[0]; r[1] = (bf16_t)a[1]; r[2] = (bf16_t)a[2]; r[3] = (bf16_t)a[3];
    r[4] = (bf16_t)b[0]; r[5] = (bf16_t)b[1]; r[6] = (bf16_t)b[2]; r[7] = (bf16_t)b[3];
    return r;
}

// ---------------- GEMM: ft = X*Wfc^T, res = X*Wres^T, a_l/a_r epilogue ----------------
// X = h viewed as [600000][64] f32 -> bf16 in-register. One wave per 16-row tile.
// mfma_f32_16x16x32_bf16: A row=lane&15, k=(lane>>4)*8+i ; B col=lane&15, same k ;
// D col=lane&15, row=(lane>>4)*4+reg  [m89-verified layout].
__global__ __launch_bounds__(256) void k_gemm(
    const float* __restrict__ h,
    const float* __restrict__ wfc,
    const float* __restrict__ wres,
    const float* __restrict__ attl,
    const float* __restrict__ attr,
    bf16_t* __restrict__ ft,
    bf16_t* __restrict__ resb,
    float* __restrict__ al,
    float* __restrict__ ar)
{
    int wid  = (blockIdx.x * blockDim.x + threadIdx.x) >> 6;
    if (wid >= ROW_TILES) return;
    int lane = threadIdx.x & 63;
    int lr = lane & 15, lg = lane >> 4;
    int r0 = wid << 4;

    const f32x4* hv = reinterpret_cast<const f32x4*>(h);
    const f32x4* wf = reinterpret_cast<const f32x4*>(wfc);
    const f32x4* wr = reinterpret_cast<const f32x4*>(wres);

    // A fragments (shared by both GEMMs): elem offset (r0+lr)*64 + ks*32 + lg*8
    int abase = (r0 + lr) * 16 + lg * 2;              // in f32x4 units
    bf16x8 a0 = cvt8(hv[abase + 0], hv[abase + 1]);
    bf16x8 a1 = cvt8(hv[abase + 8], hv[abase + 9]);

    f32x4 dfc[4], dre[4];
#pragma unroll
    for (int nt = 0; nt < 4; ++nt) {
        int bbase = (nt * 16 + lr) * 16 + lg * 2;     // W[col][k] in f32x4 units
        f32x4 z = {0.f, 0.f, 0.f, 0.f};
        bf16x8 b0 = cvt8(wf[bbase + 0], wf[bbase + 1]);
        bf16x8 b1 = cvt8(wf[bbase + 8], wf[bbase + 9]);
        z = __builtin_amdgcn_mfma_f32_16x16x32_bf16(a0, b0, z, 0, 0, 0);
        z = __builtin_amdgcn_mfma_f32_16x16x32_bf16(a1, b1, z, 0, 0, 0);
        dfc[nt] = z;
        f32x4 y = {0.f, 0.f, 0.f, 0.f};
        bf16x8 c0 = cvt8(wr[bbase + 0], wr[bbase + 1]);
        bf16x8 c1 = cvt8(wr[bbase + 8], wr[bbase + 9]);
        y = __builtin_amdgcn_mfma_f32_16x16x32_bf16(a0, c0, y, 0, 0, 0);
        y = __builtin_amdgcn_mfma_f32_16x16x32_bf16(a1, c1, y, 0, 0, 0);
        dre[nt] = y;
    }

    float pl[4] = {0, 0, 0, 0}, pr[4] = {0, 0, 0, 0};
#pragma unroll
    for (int nt = 0; nt < 4; ++nt) {
#pragma unroll
        for (int j = 0; j < 4; ++j) {
            int row = lg * 4 + j;
            int col = nt * 16 + lr;
            int r   = r0 + row;
            float vf = dfc[nt][j];
            ft[r * 64 + col]   = (bf16_t)vf;
            resb[r * 64 + col] = (bf16_t)dre[nt][j];
            int hh = r % NHEAD;
            pl[j] += vf * attl[hh * 64 + col];
            pr[j] += vf * attr[hh * 64 + col];
        }
    }
    // reduce across the 16 lanes sharing a row group (xor masks < 16 stay in-group)
#pragma unroll
    for (int j = 0; j < 4; ++j) {
#pragma unroll
        for (int m = 1; m < 16; m <<= 1) {
            pl[j] += __shfl_xor(pl[j], m);
            pr[j] += __shfl_xor(pr[j], m);
        }
    }
    if (lr == 0) {
#pragma unroll
        for (int j = 0; j < 4; ++j) {
            al[r0 + lg * 4 + j] = pl[j];
            ar[r0 + lg * 4 + j] = pr[j];
        }
    }
}

// ---------------- CSR build ----------------
__global__ __launch_bounds__(256) void k_deg(const int* __restrict__ dst, int* __restrict__ deg) {
    int i = blockIdx.x * 256 + threadIdx.x;
    if (i < N_EDGES) atomicAdd(&deg[dst[i]], 1);
}

// single block, 1024 threads, 52 nodes/thread; int4-vectorized loads (13 independent
// loads/thread instead of 49 latency-chained scalars).
__global__ __launch_bounds__(1024) void k_scan(const int* __restrict__ deg,
                                               int* __restrict__ rowptr,
                                               int* __restrict__ cursor) {
    __shared__ int s[1024];
    const int CH = 52;
    int t = threadIdx.x;
    int base = t * CH;
    int loc[CH];
    if (base + CH <= N_NODES) {
        const int4* p = reinterpret_cast<const int4*>(deg + base);  // base*4 % 16 == 0
#pragma unroll
        for (int i = 0; i < CH / 4; ++i) {
            int4 q = p[i];
            loc[4 * i + 0] = q.x; loc[4 * i + 1] = q.y;
            loc[4 * i + 2] = q.z; loc[4 * i + 3] = q.w;
        }
    } else {
#pragma unroll
        for (int i = 0; i < CH; ++i) {
            int idx = base + i;
            loc[i] = (idx < N_NODES) ? deg[idx] : 0;
        }
    }
    int sum = 0;
#pragma unroll
    for (int i = 0; i < CH; ++i) sum += loc[i];
    s[t] = sum;
    __syncthreads();
    for (int off = 1; off < 1024; off <<= 1) {
        int v = (t >= off) ? s[t - off] : 0;
        __syncthreads();
        s[t] += v;
        __syncthreads();
    }
    int run = s[t] - sum;  // exclusive prefix of this chunk
#pragma unroll
    for (int i = 0; i < CH; ++i) {
        int idx = base + i;
        if (idx < N_NODES) {
            rowptr[idx] = run;
            cursor[idx] = run;
            run += loc[i];
        }
    }
    if (t == 1023) rowptr[N_NODES] = s[1023];
}

__global__ __launch_bounds__(256) void k_fill(const int* __restrict__ src,
                                              const int* __restrict__ dst,
                                              int* __restrict__ cursor,
                                              int* __restrict__ csr_src) {
    int i = blockIdx.x * 256 + threadIdx.x;
    if (i < N_EDGES) {
        int d = dst[i];
        int pos = atomicAdd(&cursor[d], 1);
        csr_src[pos] = src[i];
    }
}

// ---------------- softmax + aggregate + residual + relu ----------------
// One wave per (dst,head); lane = feature d. Batched edge loop (BATCH=8): all
// indices load first, then al/ft gathers issue independently -> ~8x memory-level
// parallelism vs the serial chain. Branches are wave-uniform (idx same across
// lanes), no divergence. No max-subtraction (|logit| << 88, fp32-exp safe).
#define BATCH 8
__global__ __launch_bounds__(256) void k_agg(
    const int* __restrict__ rowptr, const int* __restrict__ csr_src,
    const float* __restrict__ al, const float* __restrict__ ar,
    const bf16_t* __restrict__ ft, const bf16_t* __restrict__ resb,
    float* __restrict__ out)
{
    int wid = (blockIdx.x * 256 + threadIdx.x) >> 6;
    if (wid >= NH) return;
    int lane = threadIdx.x & 63;
    int d0 = wid / NHEAD;
    int hh = wid - d0 * NHEAD;
    int beg = rowptr[d0], end = rowptr[d0 + 1];
    float r = (float)resb[wid * 64 + lane];   // issue early, needed only at the end
    float ard = ar[wid];
    float acc = 0.f, den = 0.f;
    for (int j0 = beg; j0 < end; j0 += BATCH) {
        int idx[BATCH];
        float w[BATCH], v[BATCH];
#pragma unroll
        for (int u = 0; u < BATCH; ++u) {
            int j = j0 + u;
            idx[u] = (j < end) ? csr_src[j] : -1;
        }
#pragma unroll
        for (int u = 0; u < BATCH; ++u)
            v[u] = (idx[u] >= 0) ? (float)ft[idx[u] * 768 + hh * 64 + lane] : 0.f;
#pragma unroll
        for (int u = 0; u < BATCH; ++u) {
            if (idx[u] >= 0) {
                float e = al[idx[u] * NHEAD + hh] + ard;
                e = (e > 0.f) ? e : 0.2f * e;          // leaky_relu
                w[u] = __expf(e);
            } else w[u] = 0.f;
        }
#pragma unroll
        for (int u = 0; u < BATCH; ++u) { den += w[u]; acc += w[u] * v[u]; }
    }
    float o = r + acc / den;
    out[wid * 64 + lane] = (o > 0.f ? o : 0.f);
}

extern "C" void kernel_launch(void* const* d_in, const int* in_sizes, int n_in,
                              void* d_out, int out_size, void* d_ws, size_t ws_size,
                              hipStream_t stream) {
    const float* h    = (const float*)d_in[0];
    const float* wfc  = (const float*)d_in[1];
    const float* attl = (const float*)d_in[2];
    const float* attr = (const float*)d_in[3];
    const float* wres = (const float*)d_in[4];
    const int*   src  = (const int*)d_in[5];
    const int*   dst  = (const int*)d_in[6];
    float* out = (float*)d_out;

    char* ws = (char*)d_ws;
    bf16_t* ft     = (bf16_t*)(ws + 0);          //  76,800,000 B
    bf16_t* resb   = (bf16_t*)(ws + 76800000);   //  76,800,000 B
    float*  al     = (float*)(ws + 153600000);   //   2,400,000 B
    float*  ar     = (float*)(ws + 156000000);   //   2,400,000 B
    int*    deg    = (int*)(ws + 158400000);     //     200,448 B
    int*    rowptr = (int*)(ws + 158600448);     //     200,448 B
    int*    cursor = (int*)(ws + 158800896);     //     200,448 B
    int*    csrsrc = (int*)(ws + 159001344);     //   1,000,000 B  (end ~160 MB)

    hipMemsetAsync(deg, 0, N_NODES * sizeof(int), stream);
    k_deg<<<(N_EDGES + 255) / 256, 256, 0, stream>>>(dst, deg);
    k_scan<<<1, 1024, 0, stream>>>(deg, rowptr, cursor);
    k_fill<<<(N_EDGES + 255) / 256, 256, 0, stream>>>(src, dst, cursor, csrsrc);
    k_gemm<<<ROW_TILES / 4, 256, 0, stream>>>(h, wfc, wres, attl, attr, ft, resb, al, ar);
    k_agg<<<NH / 4, 256, 0, stream>>>(rowptr, csrsrc, al, ar, ft, resb, out);
}